// Round 12
// baseline (713.737 us; speedup 1.0000x reference)
//
#include <hip/hip_runtime.h>
#include <hip/hip_bf16.h>
#include <cstdint>

#define N_NODES 100000
#define N_EDGES 1600000
#define N_TOT   1700000   // edges + self loops
#define HEADS   4
#define CH      64
#define HC      256       // HEADS*CH
#define NEG     0.2f
#define BNEPS   1e-5f
#define NPART   8
#define PART_N  12500     // N_NODES / NPART
#define BUCKET_CAP 262144 // per-partition edge capacity (expect ~212.5K, huge margin)

typedef __attribute__((ext_vector_type(8))) short short8;
typedef __attribute__((ext_vector_type(4))) float f32x4;
typedef __attribute__((ext_vector_type(2))) float f32x2;

static __device__ __forceinline__ float lrelu(float x) {
    return x > 0.f ? x : NEG * x;
}
static __device__ __forceinline__ unsigned short f2bf(float f) {
    unsigned int u = __float_as_uint(f);
    unsigned int r = (u + 0x7fffu + ((u >> 16) & 1u)) >> 16;   // RNE
    return (unsigned short)r;
}
static __device__ __forceinline__ float bflo(unsigned int v) { return __uint_as_float(v << 16); }
static __device__ __forceinline__ float bfhi(unsigned int v) { return __uint_as_float(v & 0xffff0000u); }

// ------- pass 1: dtype-detect + convert + per-dst histogram + partition buckets -------
__global__ void convert_bucket_k(const void* ei, int2* __restrict__ buckets,
                                 int* __restrict__ bfill, int* __restrict__ counts) {
    __shared__ int lcnt[NPART];
    __shared__ int lbase[NPART];
    const int* e32 = (const int*)ei;
    int t = threadIdx.x;
    // wave-local int64-vs-int32 detection: node ids < 2^17, so int64 odd words are 0
    int l = t & 63;
    unsigned long long b = __ballot(e32[2 * l + 1] == 0);
    int is64 = (__popcll(b) >= 48) ? 1 : 0;

    if (t < NPART) lcnt[t] = 0;
    __syncthreads();

    int e = blockIdx.x * 256 + t;
    int s = 0, d = 0, part = -1, pos = 0;
    if (e < N_TOT) {
        if (e < N_EDGES) {
            if (is64) {
                s = (int)((const long long*)ei)[e];
                d = (int)((const long long*)ei)[(long long)N_EDGES + e];
            } else {
                s = ((const int*)ei)[e];
                d = ((const int*)ei)[N_EDGES + e];
            }
        } else { int v = e - N_EDGES; s = v; d = v; }
        part = d / PART_N;
        pos = atomicAdd(&lcnt[part], 1);
        atomicAdd(&counts[d], 1);
    }
    __syncthreads();
    if (t < NPART) lbase[t] = atomicAdd(&bfill[t], lcnt[t]);
    __syncthreads();
    if (part >= 0)
        buckets[(size_t)part * BUCKET_CAP + lbase[part] + pos] = make_int2(s, d);
}

__global__ void scan_block(const int* in, int* out, int* bsum) {
    __shared__ int sm[256];
    int t = threadIdx.x;
    int i = blockIdx.x * 256 + t;
    int v = (i < N_NODES) ? in[i] : 0;
    int acc = v;
    sm[t] = v; __syncthreads();
    for (int d = 1; d < 256; d <<= 1) {
        int add = (t >= d) ? sm[t - d] : 0;
        __syncthreads();
        acc += add; sm[t] = acc;
        __syncthreads();
    }
    if (i < N_NODES) out[i] = acc - v;
    if (t == 255) bsum[blockIdx.x] = acc;
}

__global__ void scan_bsum(int* bsum, int nb) {
    __shared__ int sm[512];
    int t = threadIdx.x;
    int v = (t < nb) ? bsum[t] : 0;
    int acc = v;
    sm[t] = v; __syncthreads();
    for (int d = 1; d < 512; d <<= 1) {
        int add = (t >= d) ? sm[t - d] : 0;
        __syncthreads();
        acc += add; sm[t] = acc;
        __syncthreads();
    }
    if (t < nb) bsum[t] = acc - v;
}

__global__ void scan_add(int* off, const int* bsum, int* fill) {
    int i = blockIdx.x * 256 + threadIdx.x;
    if (i < N_NODES) {
        int v = off[i] + bsum[blockIdx.x];
        off[i] = v; fill[i] = v;
    }
    if (i == 0) off[N_NODES] = N_TOT;
}

// ------- pass 2: per-partition scatter (blockIdx%8 == part -> XCD-local csr writes) -------
__global__ void scatter_bucket_k(const int2* __restrict__ buckets, const int* __restrict__ bfill,
                                 int* __restrict__ fill, int* __restrict__ csr) {
    int part = blockIdx.x & (NPART - 1);
    int bi = blockIdx.x >> 3;
    int nb = gridDim.x >> 3;
    int n = bfill[part];
    const int2* bk = buckets + (size_t)part * BUCKET_CAP;
    for (int i = bi * 256 + threadIdx.x; i < n; i += nb * 256) {
        int2 sd = bk[i];
        int pos = atomicAdd(&fill[sd.y], 1);
        csr[pos] = sd.x;
    }
}

// ---- MFMA bf16 GEMM: H = A @ W[K,256], multi-tile per block (W staged once) ----
// fused: bf16 h store (coalesced via LDS repack) + per-head attention logits
template<int K, bool ABF16>
__global__ __launch_bounds__(256) void gemm_mfma_k(const void* __restrict__ Ain,
                                                   const float* __restrict__ Wf,
                                                   const float* __restrict__ as,
                                                   const float* __restrict__ ad,
                                                   unsigned short* __restrict__ hb,
                                                   float* __restrict__ es,
                                                   float* __restrict__ ed, int ntiles) {
    __shared__ __align__(16) unsigned short Bs[256 * K];   // [col][k], XOR-swizzled
    __shared__ __align__(16) unsigned short As[64 * K];    // [row][k], XOR-swizzled; scratch in epilogue
    int t = threadIdx.x;

    // stage B once: fp32 W -> bf16 transposed LDS
    for (int idx4 = t; idx4 < K * 64; idx4 += 256) {
        int k = idx4 >> 6;
        int c = (idx4 & 63) * 4;
        float4 wv = *(const float4*)(Wf + (size_t)k * HC + c);
        Bs[((c + 0) * K + k) ^ (((c + 0) & 7) << 3)] = f2bf(wv.x);
        Bs[((c + 1) * K + k) ^ (((c + 1) & 7) << 3)] = f2bf(wv.y);
        Bs[((c + 2) * K + k) ^ (((c + 2) & 7) << 3)] = f2bf(wv.z);
        Bs[((c + 3) * K + k) ^ (((c + 3) & 7) << 3)] = f2bf(wv.w);
    }

    int w = t >> 6, lane = t & 63;
    int c16 = lane & 15, kg = lane >> 4;
    int swz = (c16 & 7) << 3;
    float asv[4], adv[4];
    #pragma unroll
    for (int ct = 0; ct < 4; ++ct) {
        asv[ct] = as[w * 64 + ct * 16 + c16];
        adv[ct] = ad[w * 64 + ct * 16 + c16];
    }
    __syncthreads();

    for (int tile = blockIdx.x; tile < ntiles; tile += gridDim.x) {
        int bm = tile * 64;
        // ---- stage A (64 rows x K) ----
        #pragma unroll
        for (int i = 0; i < (64 * K / 8) / 256; ++i) {
            int cidx = i * 256 + t;
            int row = cidx / (K / 8);
            int ks = (cidx % (K / 8)) * 8;
            int grow = bm + row;
            uint4 pk = make_uint4(0, 0, 0, 0);
            if (grow < N_NODES) {
                if (ABF16) {
                    pk = *(const uint4*)((const unsigned short*)Ain + (size_t)grow * K + ks);
                } else {
                    const float* Af = (const float*)Ain + (size_t)grow * K + ks;
                    float4 v0 = *(const float4*)Af;
                    float4 v1 = *(const float4*)(Af + 4);
                    pk.x = (unsigned)f2bf(v0.x) | ((unsigned)f2bf(v0.y) << 16);
                    pk.y = (unsigned)f2bf(v0.z) | ((unsigned)f2bf(v0.w) << 16);
                    pk.z = (unsigned)f2bf(v1.x) | ((unsigned)f2bf(v1.y) << 16);
                    pk.w = (unsigned)f2bf(v1.z) | ((unsigned)f2bf(v1.w) << 16);
                }
            }
            *(uint4*)(&As[(row * K + ks) ^ ((row & 7) << 3)]) = pk;
        }
        __syncthreads();

        // ---- MFMA K-loop ----
        f32x4 acc[4][4];
        #pragma unroll
        for (int i = 0; i < 4; ++i)
            #pragma unroll
            for (int j = 0; j < 4; ++j) acc[i][j] = (f32x4)(0.f);

        #pragma unroll
        for (int kc = 0; kc < K / 32; ++kc) {
            int ko = kc * 32 + kg * 8;
            short8 af[4], bf[4];
            #pragma unroll
            for (int rs = 0; rs < 4; ++rs)
                af[rs] = *(const short8*)(&As[((16 * rs + c16) * K + ko) ^ swz]);
            #pragma unroll
            for (int ct = 0; ct < 4; ++ct) {
                int col = w * 64 + ct * 16 + c16;
                bf[ct] = *(const short8*)(&Bs[(col * K + ko) ^ swz]);
            }
            #pragma unroll
            for (int rs = 0; rs < 4; ++rs)
                #pragma unroll
                for (int ct = 0; ct < 4; ++ct)
                    acc[rs][ct] = __builtin_amdgcn_mfma_f32_16x16x32_bf16(af[rs], bf[ct], acc[rs][ct], 0, 0, 0);
        }

        // ---- logits epilogue (fp32 accumulators) ----
        #pragma unroll
        for (int rs = 0; rs < 4; ++rs) {
            float esr[4], edr[4];
            #pragma unroll
            for (int reg = 0; reg < 4; ++reg) {
                float s = 0.f, d = 0.f;
                #pragma unroll
                for (int ct = 0; ct < 4; ++ct) {
                    s += acc[rs][ct][reg] * asv[ct];
                    d += acc[rs][ct][reg] * adv[ct];
                }
                #pragma unroll
                for (int sh = 1; sh < 16; sh <<= 1) {
                    s += __shfl_xor(s, sh);
                    d += __shfl_xor(d, sh);
                }
                esr[reg] = s; edr[reg] = d;
            }
            if (c16 == 0) {
                int r0 = bm + rs * 16 + kg * 4;
                #pragma unroll
                for (int reg = 0; reg < 4; ++reg) {
                    if (r0 + reg < N_NODES) {
                        es[(size_t)(r0 + reg) * 4 + w] = esr[reg];
                        ed[(size_t)(r0 + reg) * 4 + w] = edr[reg];
                    }
                }
            }
        }
        __syncthreads();   // all As reads done -> reuse as repack scratch

        // ---- h store: repack 16 rows at a time through As, coalesced uint4 stores ----
        #pragma unroll
        for (int rs = 0; rs < 4; ++rs) {
            #pragma unroll
            for (int ct = 0; ct < 4; ++ct)
                #pragma unroll
                for (int reg = 0; reg < 4; ++reg)
                    As[(kg * 4 + reg) * 256 + w * 64 + ct * 16 + c16] = f2bf(acc[rs][ct][reg]);
            __syncthreads();
            int row16 = t >> 4, cseg = (t & 15) * 16;
            int grow = bm + rs * 16 + row16;
            if (grow < N_NODES) {
                uint4 v0 = *(const uint4*)(&As[row16 * 256 + cseg]);
                uint4 v1 = *(const uint4*)(&As[row16 * 256 + cseg + 8]);
                *(uint4*)(hb + (size_t)grow * HC + cseg) = v0;
                *(uint4*)(hb + (size_t)grow * HC + cseg + 8) = v1;
            }
            __syncthreads();
        }
    }
}

// ---- aggregate, bf16 activation output (layers 0 and 1) ----
// literal round-6 structure: straight-line body, one node per wave, lane<8 epilogue
__global__ __launch_bounds__(256) void aggregate_bf16(const unsigned short* __restrict__ h,
                                                      const float* __restrict__ es,
                                                      const float* __restrict__ ed,
                                                      const int* __restrict__ off,
                                                      const int* __restrict__ csr,
                                                      const float* __restrict__ bias,
                                                      const float* __restrict__ g,
                                                      const float* __restrict__ bb,
                                                      const float* __restrict__ mu,
                                                      const float* __restrict__ var,
                                                      unsigned short* __restrict__ xout) {
    __shared__ float wbuf[4][68][4];
    __shared__ int   sbuf[4][68];
    int wv = threadIdx.x >> 6;
    int lane = threadIdx.x & 63;
    int wid = blockIdx.x * 4 + wv;
    if (wid >= N_NODES) return;   // wave-uniform exit, no block barriers below

    // zero the 4-slot padding once (reads at jn up to 67 hit w=0, s=0)
    if (lane < 4) {
        sbuf[wv][64 + lane] = 0;
        *(float4*)(&wbuf[wv][64 + lane][0]) = make_float4(0.f, 0.f, 0.f, 0.f);
    }

    int s0 = off[wid], s1 = off[wid + 1];
    float4 edv = *(const float4*)(ed + (size_t)wid * 4);

    int half = lane >> 5;          // which edge of the pair
    int sub  = lane & 31;          // 32 lanes cover one 512B bf16 row
    int head = sub >> 3;           // 8 lanes per head
    float ds0 = 0.f, ds1 = 0.f, ds2 = 0.f, ds3 = 0.f;
    f32x2 acc2[8];
    #pragma unroll
    for (int i = 0; i < 8; ++i) acc2[i] = (f32x2)(0.f);
    const unsigned short* hsub = h + sub * 8;

    for (int base = s0; base < s1; base += 64) {
        int e = base + lane;
        float w0 = 0.f, w1 = 0.f, w2 = 0.f, w3 = 0.f;
        int s = 0;
        if (e < s1) {
            s = csr[e];
            float4 ev = *(const float4*)(es + (size_t)s * 4);
            w0 = __expf(fminf(lrelu(ev.x + edv.x), 80.f));
            w1 = __expf(fminf(lrelu(ev.y + edv.y), 80.f));
            w2 = __expf(fminf(lrelu(ev.z + edv.z), 80.f));
            w3 = __expf(fminf(lrelu(ev.w + edv.w), 80.f));
        }
        ds0 += w0; ds1 += w1; ds2 += w2; ds3 += w3;
        *(float4*)(&wbuf[wv][lane][0]) = make_float4(w0, w1, w2, w3);
        sbuf[wv][lane] = s;
        asm volatile("" ::: "memory");   // wave-synchronous LDS ordering

        // phase 2: 2 edges/iter (32 lanes x 16B per row), depth-3 pipeline, no conditionals
        int cnt2 = (min(64, s1 - base) + 1) & ~1;
        int sA = sbuf[wv][half];
        float wA = wbuf[wv][half][head];
        int sB = sbuf[wv][2 + half];
        float wB = wbuf[wv][2 + half][head];
        uint4 hA = *(const uint4*)(hsub + (size_t)sA * HC);
        uint4 hB = *(const uint4*)(hsub + (size_t)sB * HC);
        for (int j = 0; j < cnt2; j += 2) {
            int jn = j + 4 + half;
            int sC = sbuf[wv][jn];
            float wC = wbuf[wv][jn][head];
            uint4 hC = *(const uint4*)(hsub + (size_t)sC * HC);   // prefetch 2 ahead
            f32x2 wp = { wA, wA };
            f32x2 p0 = { bflo(hA.x), bfhi(hA.x) };
            f32x2 p1 = { bflo(hA.y), bfhi(hA.y) };
            f32x2 p2 = { bflo(hA.z), bfhi(hA.z) };
            f32x2 p3 = { bflo(hA.w), bfhi(hA.w) };
            asm("v_pk_fma_f32 %0, %1, %2, %0" : "+v"(acc2[0]) : "v"(p0), "v"(wp));
            asm("v_pk_fma_f32 %0, %1, %2, %0" : "+v"(acc2[1]) : "v"(p1), "v"(wp));
            asm("v_pk_fma_f32 %0, %1, %2, %0" : "+v"(acc2[2]) : "v"(p2), "v"(wp));
            asm("v_pk_fma_f32 %0, %1, %2, %0" : "+v"(acc2[3]) : "v"(p3), "v"(wp));
            hA = hB; wA = wB;
            hB = hC; wB = wC;
        }
        asm volatile("" ::: "memory");
    }

    float a0 = acc2[0][0], a1 = acc2[0][1], a2 = acc2[1][0], a3 = acc2[1][1];
    float a4 = acc2[2][0], a5 = acc2[2][1], a6 = acc2[3][0], a7 = acc2[3][1];

    a0 += __shfl_xor(a0, 32); a1 += __shfl_xor(a1, 32);
    a2 += __shfl_xor(a2, 32); a3 += __shfl_xor(a3, 32);
    a4 += __shfl_xor(a4, 32); a5 += __shfl_xor(a5, 32);
    a6 += __shfl_xor(a6, 32); a7 += __shfl_xor(a7, 32);

    #pragma unroll
    for (int d = 1; d < 64; d <<= 1) {
        ds0 += __shfl_xor(ds0, d); ds1 += __shfl_xor(ds1, d);
        ds2 += __shfl_xor(ds2, d); ds3 += __shfl_xor(ds3, d);
    }
    float den = head == 0 ? ds0 : head == 1 ? ds1 : head == 2 ? ds2 : ds3;
    float inv = 1.f / den;
    a0 *= inv; a1 *= inv; a2 *= inv; a3 *= inv;
    a4 *= inv; a5 *= inv; a6 *= inv; a7 *= inv;

    a0 += __shfl_xor(a0, 8);  a1 += __shfl_xor(a1, 8);
    a2 += __shfl_xor(a2, 8);  a3 += __shfl_xor(a3, 8);
    a4 += __shfl_xor(a4, 8);  a5 += __shfl_xor(a5, 8);
    a6 += __shfl_xor(a6, 8);  a7 += __shfl_xor(a7, 8);
    a0 += __shfl_xor(a0, 16); a1 += __shfl_xor(a1, 16);
    a2 += __shfl_xor(a2, 16); a3 += __shfl_xor(a3, 16);
    a4 += __shfl_xor(a4, 16); a5 += __shfl_xor(a5, 16);
    a6 += __shfl_xor(a6, 16); a7 += __shfl_xor(a7, 16);

    if (lane < 8) {
        int c = lane * 8;
        float av[8] = {a0, a1, a2, a3, a4, a5, a6, a7};
        float4 bi0 = *(const float4*)(bias + c), bi1 = *(const float4*)(bias + c + 4);
        float4 gv0 = *(const float4*)(g + c),    gv1 = *(const float4*)(g + c + 4);
        float4 bv0 = *(const float4*)(bb + c),   bv1 = *(const float4*)(bb + c + 4);
        float4 mv0 = *(const float4*)(mu + c),   mv1 = *(const float4*)(mu + c + 4);
        float4 vv0 = *(const float4*)(var + c),  vv1 = *(const float4*)(var + c + 4);
        float bia[8] = {bi0.x, bi0.y, bi0.z, bi0.w, bi1.x, bi1.y, bi1.z, bi1.w};
        float gg[8]  = {gv0.x, gv0.y, gv0.z, gv0.w, gv1.x, gv1.y, gv1.z, gv1.w};
        float be[8]  = {bv0.x, bv0.y, bv0.z, bv0.w, bv1.x, bv1.y, bv1.z, bv1.w};
        float mm[8]  = {mv0.x, mv0.y, mv0.z, mv0.w, mv1.x, mv1.y, mv1.z, mv1.w};
        float vv[8]  = {vv0.x, vv0.y, vv0.z, vv0.w, vv1.x, vv1.y, vv1.z, vv1.w};
        float o[8];
        #pragma unroll
        for (int k = 0; k < 8; ++k) {
            float t0 = (av[k] * 0.25f + bia[k] - mm[k]) * (gg[k] * rsqrtf(vv[k] + BNEPS)) + be[k];
            o[k] = fmaxf(t0, 0.f);
        }
        uint4 pk;
        pk.x = (unsigned)f2bf(o[0]) | ((unsigned)f2bf(o[1]) << 16);
        pk.y = (unsigned)f2bf(o[2]) | ((unsigned)f2bf(o[3]) << 16);
        pk.z = (unsigned)f2bf(o[4]) | ((unsigned)f2bf(o[5]) << 16);
        pk.w = (unsigned)f2bf(o[6]) | ((unsigned)f2bf(o[7]) << 16);
        *(uint4*)(xout + (size_t)wid * CH + c) = pk;
    }
}

// ---- aggregate, fused MLP head output (layer 2) ----
__global__ __launch_bounds__(256) void aggregate_mlp(const unsigned short* __restrict__ h,
                                                     const float* __restrict__ es,
                                                     const float* __restrict__ ed,
                                                     const int* __restrict__ off,
                                                     const int* __restrict__ csr,
                                                     const float* __restrict__ bias,
                                                     const float* __restrict__ g,
                                                     const float* __restrict__ bb,
                                                     const float* __restrict__ mu,
                                                     const float* __restrict__ var,
                                                     float* __restrict__ out,
                                                     const float* __restrict__ w1p,
                                                     const float* __restrict__ b1p,
                                                     const float* __restrict__ w2p,
                                                     const float* __restrict__ b2p) {
    __shared__ float wbuf[4][68][4];
    __shared__ int   sbuf[4][68];
    int wv = threadIdx.x >> 6;
    int lane = threadIdx.x & 63;
    int wid = blockIdx.x * 4 + wv;
    if (wid >= N_NODES) return;

    if (lane < 4) {
        sbuf[wv][64 + lane] = 0;
        *(float4*)(&wbuf[wv][64 + lane][0]) = make_float4(0.f, 0.f, 0.f, 0.f);
    }

    int s0 = off[wid], s1 = off[wid + 1];
    float4 edv = *(const float4*)(ed + (size_t)wid * 4);

    int half = lane >> 5;
    int sub  = lane & 31;
    int head = sub >> 3;
    float ds0 = 0.f, ds1 = 0.f, ds2 = 0.f, ds3 = 0.f;
    f32x2 acc2[8];
    #pragma unroll
    for (int i = 0; i < 8; ++i) acc2[i] = (f32x2)(0.f);
    const unsigned short* hsub = h + sub * 8;

    for (int base = s0; base < s1; base += 64) {
        int e = base + lane;
        float w0 = 0.f, w1 = 0.f, w2 = 0.f, w3 = 0.f;
        int s = 0;
        if (e < s1) {
            s = csr[e];
            float4 ev = *(const float4*)(es + (size_t)s * 4);
            w0 = __expf(fminf(lrelu(ev.x + edv.x), 80.f));
            w1 = __expf(fminf(lrelu(ev.y + edv.y), 80.f));
            w2 = __expf(fminf(lrelu(ev.z + edv.z), 80.f));
            w3 = __expf(fminf(lrelu(ev.w + edv.w), 80.f));
        }
        ds0 += w0; ds1 += w1; ds2 += w2; ds3 += w3;
        *(float4*)(&wbuf[wv][lane][0]) = make_float4(w0, w1, w2, w3);
        sbuf[wv][lane] = s;
        asm volatile("" ::: "memory");

        int cnt2 = (min(64, s1 - base) + 1) & ~1;
        int sA = sbuf[wv][half];
        float wA = wbuf[wv][half][head];
        int sB = sbuf[wv][2 + half];
        float wB = wbuf[wv][2 + half][head];
        uint4 hA = *(const uint4*)(hsub + (size_t)sA * HC);
        uint4 hB = *(const uint4*)(hsub + (size_t)sB * HC);
        for (int j = 0; j < cnt2; j += 2) {
            int jn = j + 4 + half;
            int sC = sbuf[wv][jn];
            float wC = wbuf[wv][jn][head];
            uint4 hC = *(const uint4*)(hsub + (size_t)sC * HC);
            f32x2 wp = { wA, wA };
            f32x2 p0 = { bflo(hA.x), bfhi(hA.x) };
            f32x2 p1 = { bflo(hA.y), bfhi(hA.y) };
            f32x2 p2 = { bflo(hA.z), bfhi(hA.z) };
            f32x2 p3 = { bflo(hA.w), bfhi(hA.w) };
            asm("v_pk_fma_f32 %0, %1, %2, %0" : "+v"(acc2[0]) : "v"(p0), "v"(wp));
            asm("v_pk_fma_f32 %0, %1, %2, %0" : "+v"(acc2[1]) : "v"(p1), "v"(wp));
            asm("v_pk_fma_f32 %0, %1, %2, %0" : "+v"(acc2[2]) : "v"(p2), "v"(wp));
            asm("v_pk_fma_f32 %0, %1, %2, %0" : "+v"(acc2[3]) : "v"(p3), "v"(wp));
            hA = hB; wA = wB;
            hB = hC; wB = wC;
        }
        asm volatile("" ::: "memory");
    }

    float a0 = acc2[0][0], a1 = acc2[0][1], a2 = acc2[1][0], a3 = acc2[1][1];
    float a4 = acc2[2][0], a5 = acc2[2][1], a6 = acc2[3][0], a7 = acc2[3][1];

    a0 += __shfl_xor(a0, 32); a1 += __shfl_xor(a1, 32);
    a2 += __shfl_xor(a2, 32); a3 += __shfl_xor(a3, 32);
    a4 += __shfl_xor(a4, 32); a5 += __shfl_xor(a5, 32);
    a6 += __shfl_xor(a6, 32); a7 += __shfl_xor(a7, 32);

    #pragma unroll
    for (int d = 1; d < 64; d <<= 1) {
        ds0 += __shfl_xor(ds0, d); ds1 += __shfl_xor(ds1, d);
        ds2 += __shfl_xor(ds2, d); ds3 += __shfl_xor(ds3, d);
    }
    float den = head == 0 ? ds0 : head == 1 ? ds1 : head == 2 ? ds2 : ds3;
    float inv = 1.f / den;
    a0 *= inv; a1 *= inv; a2 *= inv; a3 *= inv;
    a4 *= inv; a5 *= inv; a6 *= inv; a7 *= inv;

    a0 += __shfl_xor(a0, 8);  a1 += __shfl_xor(a1, 8);
    a2 += __shfl_xor(a2, 8);  a3 += __shfl_xor(a3, 8);
    a4 += __shfl_xor(a4, 8);  a5 += __shfl_xor(a5, 8);
    a6 += __shfl_xor(a6, 8);  a7 += __shfl_xor(a7, 8);
    a0 += __shfl_xor(a0, 16); a1 += __shfl_xor(a1, 16);
    a2 += __shfl_xor(a2, 16); a3 += __shfl_xor(a3, 16);
    a4 += __shfl_xor(a4, 16); a5 += __shfl_xor(a5, 16);
    a6 += __shfl_xor(a6, 16); a7 += __shfl_xor(a7, 16);

    if (lane < 8) {
        int c = lane * 8;
        float av[8] = {a0, a1, a2, a3, a4, a5, a6, a7};
        float4 bi0 = *(const float4*)(bias + c), bi1 = *(const float4*)(bias + c + 4);
        float4 gv0 = *(const float4*)(g + c),    gv1 = *(const float4*)(g + c + 4);
        float4 bv0 = *(const float4*)(bb + c),   bv1 = *(const float4*)(bb + c + 4);
        float4 mv0 = *(const float4*)(mu + c),   mv1 = *(const float4*)(mu + c + 4);
        float4 vv0 = *(const float4*)(var + c),  vv1 = *(const float4*)(var + c + 4);
        float bia[8] = {bi0.x, bi0.y, bi0.z, bi0.w, bi1.x, bi1.y, bi1.z, bi1.w};
        float gg[8]  = {gv0.x, gv0.y, gv0.z, gv0.w, gv1.x, gv1.y, gv1.z, gv1.w};
        float be[8]  = {bv0.x, bv0.y, bv0.z, bv0.w, bv1.x, bv1.y, bv1.z, bv1.w};
        float mm[8]  = {mv0.x, mv0.y, mv0.z, mv0.w, mv1.x, mv1.y, mv1.z, mv1.w};
        float vv[8]  = {vv0.x, vv0.y, vv0.z, vv0.w, vv1.x, vv1.y, vv1.z, vv1.w};
        float o[8];
        #pragma unroll
        for (int k = 0; k < 8; ++k) {
            float t0 = (av[k] * 0.25f + bia[k] - mm[k]) * (gg[k] * rsqrtf(vv[k] + BNEPS)) + be[k];
            o[k] = fmaxf(t0, 0.f);
        }
        // hand the row to the whole wave via LDS (wbuf slots 0..15 are free now)
        *(float4*)(&wbuf[wv][lane * 2][0])     = make_float4(o[0], o[1], o[2], o[3]);
        *(float4*)(&wbuf[wv][lane * 2 + 1][0]) = make_float4(o[4], o[5], o[6], o[7]);
    }
    asm volatile("" ::: "memory");   // wave-synchronous LDS ordering
    const float* xv = &wbuf[wv][0][0];
    int k32 = lane & 31;
    int hi = lane >> 5;              // half: c-range [0,32) or [32,64)
    float y = hi ? 0.f : b1p[k32];
    #pragma unroll
    for (int i = 0; i < 32; ++i) {
        int cc = hi * 32 + i;
        y = fmaf(xv[cc], w1p[cc * 32 + k32], y);   // LDS broadcast * coalesced 128B line
    }
    y += __shfl_xor(y, 32);          // combine c-halves
    float z = fmaxf(y, 0.f) * w2p[k32];
    z += __shfl_xor(z, 1);
    z += __shfl_xor(z, 2);
    z += __shfl_xor(z, 4);
    z += __shfl_xor(z, 8);
    z += __shfl_xor(z, 16);
    if (lane == 0) out[wid] = z + b2p[0];
}

extern "C" void kernel_launch(void* const* d_in, const int* in_sizes, int n_in,
                              void* d_out, int out_size, void* d_ws, size_t ws_size,
                              hipStream_t stream) {
    const float* x0    = (const float*)d_in[0];
    const void*  ei    = d_in[1];
    const float* W0    = (const float*)d_in[2];
    const float* Wl    = (const float*)d_in[3];
    const float* asrc  = (const float*)d_in[4];
    const float* adst  = (const float*)d_in[5];
    const float* cbias = (const float*)d_in[6];
    const float* bng   = (const float*)d_in[7];
    const float* bnb   = (const float*)d_in[8];
    const float* bnm   = (const float*)d_in[9];
    const float* bnv   = (const float*)d_in[10];
    const float* l1w   = (const float*)d_in[11];
    const float* l1b   = (const float*)d_in[12];
    const float* l2w   = (const float*)d_in[13];
    const float* l2b   = (const float*)d_in[14];
    float* out = (float*)d_out;

    char* p = (char*)d_ws;
    auto alloc = [&](size_t bytes) { char* r = p; p += (bytes + 255) & ~(size_t)255; return r; };
    unsigned short* hb   = (unsigned short*)alloc((size_t)N_NODES * HC * 2);  // 51.2 MB
    unsigned short* xb0  = (unsigned short*)alloc((size_t)N_NODES * CH * 2);  // 12.8 MB
    unsigned short* xb1  = (unsigned short*)alloc((size_t)N_NODES * CH * 2);  // 12.8 MB
    float* es   = (float*)alloc((size_t)N_NODES * 4 * 4);
    float* ed   = (float*)alloc((size_t)N_NODES * 4 * 4);
    int* counts = (int*)alloc((size_t)(N_NODES + 64) * 4);   // counts + bfill in one memset region
    int* bfill  = counts + N_NODES;
    int* off    = (int*)alloc((size_t)(N_NODES + 1) * 4);
    int* fill   = (int*)alloc((size_t)N_NODES * 4);
    int* bsum   = (int*)alloc(512 * 4);
    int2* buckets = (int2*)alloc((size_t)NPART * BUCKET_CAP * 8);             // 16.8 MB
    int* csr    = (int*)alloc((size_t)N_TOT * 4);

    int nbScan = (N_NODES + 255) / 256;             // 391
    int ntiles = (N_NODES + 63) / 64;               // 1563
    hipMemsetAsync(counts, 0, (size_t)(N_NODES + 64) * 4, stream);
    convert_bucket_k<<<(N_TOT + 255) / 256, 256, 0, stream>>>(ei, buckets, bfill, counts);
    scan_block<<<nbScan, 256, 0, stream>>>(counts, off, bsum);
    scan_bsum<<<1, 512, 0, stream>>>(bsum, nbScan);
    scan_add<<<nbScan, 256, 0, stream>>>(off, bsum, fill);
    scatter_bucket_k<<<NPART * 64, 256, 0, stream>>>(buckets, bfill, fill, csr);

    int nagg = (N_NODES + 3) / 4;   // 25000
    // layer 0: fp32 x -> bf16 out
    gemm_mfma_k<128, false><<<512, 256, 0, stream>>>(x0, W0, asrc, adst, hb, es, ed, ntiles);
    aggregate_bf16<<<nagg, 256, 0, stream>>>(hb, es, ed, off, csr,
        cbias, bng, bnb, bnm, bnv, xb0);
    // layer 1: bf16 x -> bf16 out
    gemm_mfma_k<64, true><<<1024, 256, 0, stream>>>(xb0, Wl, asrc + HC, adst + HC, hb, es, ed, ntiles);
    aggregate_bf16<<<nagg, 256, 0, stream>>>(hb, es, ed, off, csr,
        cbias + CH, bng + CH, bnb + CH, bnm + CH, bnv + CH, xb1);
    // layer 2: bf16 x -> fused MLP -> out
    gemm_mfma_k<64, true><<<1024, 256, 0, stream>>>(xb1, Wl + (size_t)CH * HC, asrc + 2 * HC, adst + 2 * HC, hb, es, ed, ntiles);
    aggregate_mlp<<<nagg, 256, 0, stream>>>(hb, es, ed, off, csr,
        cbias + 2 * CH, bng + 2 * CH, bnb + 2 * CH, bnm + 2 * CH, bnv + 2 * CH, out,
        l1w, l1b, l2w, l2b);
}

// Round 13
// 695.329 us; speedup vs baseline: 1.0265x; 1.0265x over previous
//
#include <hip/hip_runtime.h>
#include <hip/hip_bf16.h>
#include <cstdint>

#define N_NODES 100000
#define N_EDGES 1600000
#define N_TOT   1700000   // edges + self loops
#define HEADS   4
#define CH      64
#define HC      256       // HEADS*CH
#define NEG     0.2f
#define BNEPS   1e-5f
#define NPART   8
#define PART_N  12500     // N_NODES / NPART
#define CHUNK_E 16384

typedef __attribute__((ext_vector_type(8))) short short8;
typedef __attribute__((ext_vector_type(4))) float f32x4;
typedef __attribute__((ext_vector_type(2))) float f32x2;

static __device__ __forceinline__ float lrelu(float x) {
    return x > 0.f ? x : NEG * x;
}
static __device__ __forceinline__ unsigned short f2bf(float f) {
    unsigned int u = __float_as_uint(f);
    unsigned int r = (u + 0x7fffu + ((u >> 16) & 1u)) >> 16;   // RNE
    return (unsigned short)r;
}
static __device__ __forceinline__ float bflo(unsigned int v) { return __uint_as_float(v << 16); }
static __device__ __forceinline__ float bfhi(unsigned int v) { return __uint_as_float(v & 0xffff0000u); }

// ---------------- fused dtype-detect + convert + histogram ----------------
__global__ void convert_hist_k(const void* ei,
                               int* __restrict__ src32, int* __restrict__ dst32,
                               int* __restrict__ counts) {
    // wave-local int64-vs-int32 detection: node ids < 2^17, so int64 odd words are 0
    const int* e32 = (const int*)ei;
    int l = threadIdx.x & 63;
    unsigned long long b = __ballot(e32[2 * l + 1] == 0);
    int is64 = (__popcll(b) >= 48) ? 1 : 0;

    int e = blockIdx.x * 256 + threadIdx.x;
    if (e >= N_TOT) return;
    int s, d;
    if (e < N_EDGES) {
        if (is64) {
            s = (int)((const long long*)ei)[e];
            d = (int)((const long long*)ei)[(long long)N_EDGES + e];
        } else {
            s = ((const int*)ei)[e];
            d = ((const int*)ei)[N_EDGES + e];
        }
    } else { int v = e - N_EDGES; s = v; d = v; }
    src32[e] = s; dst32[e] = d;
    atomicAdd(&counts[d], 1);
}

__global__ void scan_block(const int* in, int* out, int* bsum) {
    __shared__ int sm[256];
    int t = threadIdx.x;
    int i = blockIdx.x * 256 + t;
    int v = (i < N_NODES) ? in[i] : 0;
    int acc = v;
    sm[t] = v; __syncthreads();
    for (int d = 1; d < 256; d <<= 1) {
        int add = (t >= d) ? sm[t - d] : 0;
        __syncthreads();
        acc += add; sm[t] = acc;
        __syncthreads();
    }
    if (i < N_NODES) out[i] = acc - v;
    if (t == 255) bsum[blockIdx.x] = acc;
}

__global__ void scan_bsum(int* bsum, int nb) {
    __shared__ int sm[512];
    int t = threadIdx.x;
    int v = (t < nb) ? bsum[t] : 0;
    int acc = v;
    sm[t] = v; __syncthreads();
    for (int d = 1; d < 512; d <<= 1) {
        int add = (t >= d) ? sm[t - d] : 0;
        __syncthreads();
        acc += add; sm[t] = acc;
        __syncthreads();
    }
    if (t < nb) bsum[t] = acc - v;
}

__global__ void scan_add(int* off, const int* bsum, int* fill) {
    int i = blockIdx.x * 256 + threadIdx.x;
    if (i < N_NODES) {
        int v = off[i] + bsum[blockIdx.x];
        off[i] = v; fill[i] = v;
    }
    if (i == 0) off[N_NODES] = N_TOT;
}

// dst-partitioned scatter: each partition's csr range is written by one XCD's blocks
__global__ void scatter_part_k(const int* __restrict__ src32, const int* __restrict__ dst32,
                               int* __restrict__ fill, int* __restrict__ csr) {
    int part = blockIdx.x & (NPART - 1), chunk = blockIdx.x / NPART;
    int lo = part * PART_N, hi = lo + PART_N;
    int base = chunk * CHUNK_E;
    int end = min(base + CHUNK_E, N_TOT);
    for (int i = base + threadIdx.x; i < end; i += 256) {
        int d = dst32[i];
        if (d >= lo && d < hi) {
            int s = src32[i];
            int pos = atomicAdd(&fill[d], 1);
            csr[pos] = s;
        }
    }
}

// ---- MFMA bf16 GEMM: H = A @ W[K,256], multi-tile per block (W staged once) ----
// fused: bf16 h store (coalesced via LDS repack) + per-head attention logits
template<int K, bool ABF16>
__global__ __launch_bounds__(256) void gemm_mfma_k(const void* __restrict__ Ain,
                                                   const float* __restrict__ Wf,
                                                   const float* __restrict__ as,
                                                   const float* __restrict__ ad,
                                                   unsigned short* __restrict__ hb,
                                                   float* __restrict__ es,
                                                   float* __restrict__ ed, int ntiles) {
    __shared__ __align__(16) unsigned short Bs[256 * K];   // [col][k], XOR-swizzled
    __shared__ __align__(16) unsigned short As[64 * K];    // [row][k], XOR-swizzled; scratch in epilogue
    int t = threadIdx.x;

    // stage B once: fp32 W -> bf16 transposed LDS
    for (int idx4 = t; idx4 < K * 64; idx4 += 256) {
        int k = idx4 >> 6;
        int c = (idx4 & 63) * 4;
        float4 wv = *(const float4*)(Wf + (size_t)k * HC + c);
        Bs[((c + 0) * K + k) ^ (((c + 0) & 7) << 3)] = f2bf(wv.x);
        Bs[((c + 1) * K + k) ^ (((c + 1) & 7) << 3)] = f2bf(wv.y);
        Bs[((c + 2) * K + k) ^ (((c + 2) & 7) << 3)] = f2bf(wv.z);
        Bs[((c + 3) * K + k) ^ (((c + 3) & 7) << 3)] = f2bf(wv.w);
    }
    // stage A (fp32 -> bf16, row-major)
    int w = t >> 6, lane = t & 63;
    int c16 = lane & 15, kg = lane >> 4;
    int swz = (c16 & 7) << 3;
    float asv[4], adv[4];
    #pragma unroll
    for (int ct = 0; ct < 4; ++ct) {
        asv[ct] = as[w * 64 + ct * 16 + c16];
        adv[ct] = ad[w * 64 + ct * 16 + c16];
    }
    __syncthreads();

    for (int tile = blockIdx.x; tile < ntiles; tile += gridDim.x) {
        int bm = tile * 64;
        // ---- stage A (64 rows x K) ----
        #pragma unroll
        for (int i = 0; i < (64 * K / 8) / 256; ++i) {
            int cidx = i * 256 + t;
            int row = cidx / (K / 8);
            int ks = (cidx % (K / 8)) * 8;
            int grow = bm + row;
            uint4 pk = make_uint4(0, 0, 0, 0);
            if (grow < N_NODES) {
                if (ABF16) {
                    pk = *(const uint4*)((const unsigned short*)Ain + (size_t)grow * K + ks);
                } else {
                    const float* Af = (const float*)Ain + (size_t)grow * K + ks;
                    float4 v0 = *(const float4*)Af;
                    float4 v1 = *(const float4*)(Af + 4);
                    pk.x = (unsigned)f2bf(v0.x) | ((unsigned)f2bf(v0.y) << 16);
                    pk.y = (unsigned)f2bf(v0.z) | ((unsigned)f2bf(v0.w) << 16);
                    pk.z = (unsigned)f2bf(v1.x) | ((unsigned)f2bf(v1.y) << 16);
                    pk.w = (unsigned)f2bf(v1.z) | ((unsigned)f2bf(v1.w) << 16);
                }
            }
            *(uint4*)(&As[(row * K + ks) ^ ((row & 7) << 3)]) = pk;
        }
        __syncthreads();

        // ---- MFMA K-loop ----
        f32x4 acc[4][4];
        #pragma unroll
        for (int i = 0; i < 4; ++i)
            #pragma unroll
            for (int j = 0; j < 4; ++j) acc[i][j] = (f32x4)(0.f);

        #pragma unroll
        for (int kc = 0; kc < K / 32; ++kc) {
            int ko = kc * 32 + kg * 8;
            short8 af[4], bf[4];
            #pragma unroll
            for (int rs = 0; rs < 4; ++rs)
                af[rs] = *(const short8*)(&As[((16 * rs + c16) * K + ko) ^ swz]);
            #pragma unroll
            for (int ct = 0; ct < 4; ++ct) {
                int col = w * 64 + ct * 16 + c16;
                bf[ct] = *(const short8*)(&Bs[(col * K + ko) ^ swz]);
            }
            #pragma unroll
            for (int rs = 0; rs < 4; ++rs)
                #pragma unroll
                for (int ct = 0; ct < 4; ++ct)
                    acc[rs][ct] = __builtin_amdgcn_mfma_f32_16x16x32_bf16(af[rs], bf[ct], acc[rs][ct], 0, 0, 0);
        }

        // ---- logits epilogue (fp32 accumulators) ----
        #pragma unroll
        for (int rs = 0; rs < 4; ++rs) {
            float esr[4], edr[4];
            #pragma unroll
            for (int reg = 0; reg < 4; ++reg) {
                float s = 0.f, d = 0.f;
                #pragma unroll
                for (int ct = 0; ct < 4; ++ct) {
                    s += acc[rs][ct][reg] * asv[ct];
                    d += acc[rs][ct][reg] * adv[ct];
                }
                #pragma unroll
                for (int sh = 1; sh < 16; sh <<= 1) {
                    s += __shfl_xor(s, sh);
                    d += __shfl_xor(d, sh);
                }
                esr[reg] = s; edr[reg] = d;
            }
            if (c16 == 0) {
                int r0 = bm + rs * 16 + kg * 4;
                #pragma unroll
                for (int reg = 0; reg < 4; ++reg) {
                    if (r0 + reg < N_NODES) {
                        es[(size_t)(r0 + reg) * 4 + w] = esr[reg];
                        ed[(size_t)(r0 + reg) * 4 + w] = edr[reg];
                    }
                }
            }
        }
        __syncthreads();   // all As reads done -> reuse as repack scratch

        // ---- h store: repack 16 rows at a time through As, coalesced uint4 stores ----
        #pragma unroll
        for (int rs = 0; rs < 4; ++rs) {
            #pragma unroll
            for (int ct = 0; ct < 4; ++ct)
                #pragma unroll
                for (int reg = 0; reg < 4; ++reg)
                    As[(kg * 4 + reg) * 256 + w * 64 + ct * 16 + c16] = f2bf(acc[rs][ct][reg]);
            __syncthreads();
            int row16 = t >> 4, cseg = (t & 15) * 16;
            int grow = bm + rs * 16 + row16;
            if (grow < N_NODES) {
                uint4 v0 = *(const uint4*)(&As[row16 * 256 + cseg]);
                uint4 v1 = *(const uint4*)(&As[row16 * 256 + cseg + 8]);
                *(uint4*)(hb + (size_t)grow * HC + cseg) = v0;
                *(uint4*)(hb + (size_t)grow * HC + cseg + 8) = v1;
            }
            __syncthreads();
        }
    }
}

// ---- aggregation: edge softmax + weighted bf16 gather + BN + ReLU ----
// depth-3 gather pipeline, padded LDS (no inner-loop conditionals), packed v_pk_fma_f32
template<bool OUTBF16>
__global__ __launch_bounds__(256) void aggregate_k(const unsigned short* __restrict__ h,
                                                   const float* __restrict__ es,
                                                   const float* __restrict__ ed,
                                                   const int* __restrict__ off,
                                                   const int* __restrict__ csr,
                                                   const float* __restrict__ bias,
                                                   const float* __restrict__ g,
                                                   const float* __restrict__ bb,
                                                   const float* __restrict__ mu,
                                                   const float* __restrict__ var,
                                                   void* __restrict__ xout) {
    __shared__ float wbuf[4][68][4];
    __shared__ int   sbuf[4][68];
    int wv = threadIdx.x >> 6;
    int lane = threadIdx.x & 63;
    int wid = blockIdx.x * 4 + wv;
    if (wid >= N_NODES) return;   // wave-uniform exit, no block barriers below

    // zero the 4-slot padding once (reads at jn up to 67 hit w=0, s=0)
    if (lane < 4) {
        sbuf[wv][64 + lane] = 0;
        *(float4*)(&wbuf[wv][64 + lane][0]) = make_float4(0.f, 0.f, 0.f, 0.f);
    }

    int s0 = off[wid], s1 = off[wid + 1];
    float4 edv = *(const float4*)(ed + (size_t)wid * 4);

    int half = lane >> 5;          // which edge of the pair
    int sub  = lane & 31;          // 32 lanes cover one 512B bf16 row
    int head = sub >> 3;           // 8 lanes per head
    float ds0 = 0.f, ds1 = 0.f, ds2 = 0.f, ds3 = 0.f;
    f32x2 acc2[8];
    #pragma unroll
    for (int i = 0; i < 8; ++i) acc2[i] = (f32x2)(0.f);
    const unsigned short* hsub = h + sub * 8;

    for (int base = s0; base < s1; base += 64) {
        int e = base + lane;
        float w0 = 0.f, w1 = 0.f, w2 = 0.f, w3 = 0.f;
        int s = 0;
        if (e < s1) {
            s = csr[e];
            float4 ev = *(const float4*)(es + (size_t)s * 4);
            w0 = __expf(fminf(lrelu(ev.x + edv.x), 80.f));
            w1 = __expf(fminf(lrelu(ev.y + edv.y), 80.f));
            w2 = __expf(fminf(lrelu(ev.z + edv.z), 80.f));
            w3 = __expf(fminf(lrelu(ev.w + edv.w), 80.f));
        }
        ds0 += w0; ds1 += w1; ds2 += w2; ds3 += w3;
        *(float4*)(&wbuf[wv][lane][0]) = make_float4(w0, w1, w2, w3);
        sbuf[wv][lane] = s;
        asm volatile("" ::: "memory");   // wave-synchronous LDS ordering

        // phase 2: 2 edges/iter (32 lanes x 16B per row), depth-3 pipeline, no conditionals
        int cnt2 = (min(64, s1 - base) + 1) & ~1;
        int sA = sbuf[wv][half];
        float wA = wbuf[wv][half][head];
        int sB = sbuf[wv][2 + half];
        float wB = wbuf[wv][2 + half][head];
        uint4 hA = *(const uint4*)(hsub + (size_t)sA * HC);
        uint4 hB = *(const uint4*)(hsub + (size_t)sB * HC);
        for (int j = 0; j < cnt2; j += 2) {
            int jn = j + 4 + half;
            int sC = sbuf[wv][jn];
            float wC = wbuf[wv][jn][head];
            uint4 hC = *(const uint4*)(hsub + (size_t)sC * HC);   // prefetch 2 ahead
            f32x2 wp = { wA, wA };
            f32x2 p0 = { bflo(hA.x), bfhi(hA.x) };
            f32x2 p1 = { bflo(hA.y), bfhi(hA.y) };
            f32x2 p2 = { bflo(hA.z), bfhi(hA.z) };
            f32x2 p3 = { bflo(hA.w), bfhi(hA.w) };
            asm("v_pk_fma_f32 %0, %1, %2, %0" : "+v"(acc2[0]) : "v"(p0), "v"(wp));
            asm("v_pk_fma_f32 %0, %1, %2, %0" : "+v"(acc2[1]) : "v"(p1), "v"(wp));
            asm("v_pk_fma_f32 %0, %1, %2, %0" : "+v"(acc2[2]) : "v"(p2), "v"(wp));
            asm("v_pk_fma_f32 %0, %1, %2, %0" : "+v"(acc2[3]) : "v"(p3), "v"(wp));
            hA = hB; wA = wB;
            hB = hC; wB = wC;
        }
        asm volatile("" ::: "memory");
    }

    // unpack pair accumulators to 8 scalars (even/odd channel within each half-word pair)
    float a0 = acc2[0][0], a1 = acc2[0][1], a2 = acc2[1][0], a3 = acc2[1][1];
    float a4 = acc2[2][0], a5 = acc2[2][1], a6 = acc2[3][0], a7 = acc2[3][1];

    a0 += __shfl_xor(a0, 32); a1 += __shfl_xor(a1, 32);
    a2 += __shfl_xor(a2, 32); a3 += __shfl_xor(a3, 32);
    a4 += __shfl_xor(a4, 32); a5 += __shfl_xor(a5, 32);
    a6 += __shfl_xor(a6, 32); a7 += __shfl_xor(a7, 32);

    #pragma unroll
    for (int d = 1; d < 64; d <<= 1) {
        ds0 += __shfl_xor(ds0, d); ds1 += __shfl_xor(ds1, d);
        ds2 += __shfl_xor(ds2, d); ds3 += __shfl_xor(ds3, d);
    }
    float den = head == 0 ? ds0 : head == 1 ? ds1 : head == 2 ? ds2 : ds3;
    float inv = 1.f / den;
    a0 *= inv; a1 *= inv; a2 *= inv; a3 *= inv;
    a4 *= inv; a5 *= inv; a6 *= inv; a7 *= inv;

    a0 += __shfl_xor(a0, 8);  a1 += __shfl_xor(a1, 8);
    a2 += __shfl_xor(a2, 8);  a3 += __shfl_xor(a3, 8);
    a4 += __shfl_xor(a4, 8);  a5 += __shfl_xor(a5, 8);
    a6 += __shfl_xor(a6, 8);  a7 += __shfl_xor(a7, 8);
    a0 += __shfl_xor(a0, 16); a1 += __shfl_xor(a1, 16);
    a2 += __shfl_xor(a2, 16); a3 += __shfl_xor(a3, 16);
    a4 += __shfl_xor(a4, 16); a5 += __shfl_xor(a5, 16);
    a6 += __shfl_xor(a6, 16); a7 += __shfl_xor(a7, 16);

    if (lane < 8) {
        int c = lane * 8;
        float av[8] = {a0, a1, a2, a3, a4, a5, a6, a7};
        float4 bi0 = *(const float4*)(bias + c), bi1 = *(const float4*)(bias + c + 4);
        float4 gv0 = *(const float4*)(g + c),    gv1 = *(const float4*)(g + c + 4);
        float4 bv0 = *(const float4*)(bb + c),   bv1 = *(const float4*)(bb + c + 4);
        float4 mv0 = *(const float4*)(mu + c),   mv1 = *(const float4*)(mu + c + 4);
        float4 vv0 = *(const float4*)(var + c),  vv1 = *(const float4*)(var + c + 4);
        float bia[8] = {bi0.x, bi0.y, bi0.z, bi0.w, bi1.x, bi1.y, bi1.z, bi1.w};
        float gg[8]  = {gv0.x, gv0.y, gv0.z, gv0.w, gv1.x, gv1.y, gv1.z, gv1.w};
        float be[8]  = {bv0.x, bv0.y, bv0.z, bv0.w, bv1.x, bv1.y, bv1.z, bv1.w};
        float mm[8]  = {mv0.x, mv0.y, mv0.z, mv0.w, mv1.x, mv1.y, mv1.z, mv1.w};
        float vv[8]  = {vv0.x, vv0.y, vv0.z, vv0.w, vv1.x, vv1.y, vv1.z, vv1.w};
        float o[8];
        #pragma unroll
        for (int k = 0; k < 8; ++k) {
            float t0 = (av[k] * 0.25f + bia[k] - mm[k]) * (gg[k] * rsqrtf(vv[k] + BNEPS)) + be[k];
            o[k] = fmaxf(t0, 0.f);
        }
        if (OUTBF16) {
            uint4 pk;
            pk.x = (unsigned)f2bf(o[0]) | ((unsigned)f2bf(o[1]) << 16);
            pk.y = (unsigned)f2bf(o[2]) | ((unsigned)f2bf(o[3]) << 16);
            pk.z = (unsigned)f2bf(o[4]) | ((unsigned)f2bf(o[5]) << 16);
            pk.w = (unsigned)f2bf(o[6]) | ((unsigned)f2bf(o[7]) << 16);
            *(uint4*)((unsigned short*)xout + (size_t)wid * CH + c) = pk;
        } else {
            *(float4*)((float*)xout + (size_t)wid * CH + c)     = make_float4(o[0], o[1], o[2], o[3]);
            *(float4*)((float*)xout + (size_t)wid * CH + c + 4) = make_float4(o[4], o[5], o[6], o[7]);
        }
    }
}

// ---------------- MLP head: out = relu(x@W1+b1)@W2+b2 ----------------
__global__ __launch_bounds__(256) void mlp_k(const float* __restrict__ x,
                                             const float* __restrict__ w1,
                                             const float* __restrict__ b1,
                                             const float* __restrict__ w2,
                                             const float* __restrict__ b2,
                                             float* __restrict__ out) {
    __shared__ float w1s[CH * 32];
    __shared__ float w2s[32];
    __shared__ float b1s[32];
    int t = threadIdx.x;
    for (int i = t; i < CH * 32; i += 256) w1s[i] = w1[i];
    if (t < 32) { w2s[t] = w2[t]; b1s[t] = b1[t]; }
    __syncthreads();
    int n = blockIdx.x * 256 + t;
    if (n >= N_NODES) return;
    float y[32];
    #pragma unroll
    for (int j = 0; j < 32; ++j) y[j] = b1s[j];
    const float* xr = x + (size_t)n * CH;
    for (int c4 = 0; c4 < 16; ++c4) {
        float4 xv = *(const float4*)(xr + c4 * 4);
        const float* wr = &w1s[c4 * 4 * 32];
        #pragma unroll
        for (int j = 0; j < 32; ++j)
            y[j] += xv.x * wr[j] + xv.y * wr[32 + j] + xv.z * wr[64 + j] + xv.w * wr[96 + j];
    }
    float o = b2[0];
    #pragma unroll
    for (int j = 0; j < 32; ++j) o += fmaxf(y[j], 0.f) * w2s[j];
    out[n] = o;
}

extern "C" void kernel_launch(void* const* d_in, const int* in_sizes, int n_in,
                              void* d_out, int out_size, void* d_ws, size_t ws_size,
                              hipStream_t stream) {
    const float* x0    = (const float*)d_in[0];
    const void*  ei    = d_in[1];
    const float* W0    = (const float*)d_in[2];
    const float* Wl    = (const float*)d_in[3];
    const float* asrc  = (const float*)d_in[4];
    const float* adst  = (const float*)d_in[5];
    const float* cbias = (const float*)d_in[6];
    const float* bng   = (const float*)d_in[7];
    const float* bnb   = (const float*)d_in[8];
    const float* bnm   = (const float*)d_in[9];
    const float* bnv   = (const float*)d_in[10];
    const float* l1w   = (const float*)d_in[11];
    const float* l1b   = (const float*)d_in[12];
    const float* l2w   = (const float*)d_in[13];
    const float* l2b   = (const float*)d_in[14];
    float* out = (float*)d_out;

    char* p = (char*)d_ws;
    auto alloc = [&](size_t bytes) { char* r = p; p += (bytes + 255) & ~(size_t)255; return r; };
    unsigned short* hb   = (unsigned short*)alloc((size_t)N_NODES * HC * 2);  // 51.2 MB
    unsigned short* xb0  = (unsigned short*)alloc((size_t)N_NODES * CH * 2);  // 12.8 MB
    unsigned short* xb1  = (unsigned short*)alloc((size_t)N_NODES * CH * 2);  // 12.8 MB
    float* xf32 = (float*)alloc((size_t)N_NODES * CH * 4);                    // 25.6 MB
    float* es   = (float*)alloc((size_t)N_NODES * 4 * 4);
    float* ed   = (float*)alloc((size_t)N_NODES * 4 * 4);
    int* counts = (int*)alloc((size_t)N_NODES * 4);
    int* off    = (int*)alloc((size_t)(N_NODES + 1) * 4);
    int* fill   = (int*)alloc((size_t)N_NODES * 4);
    int* bsum   = (int*)alloc(512 * 4);
    int* src32  = (int*)alloc((size_t)N_TOT * 4);
    int* dst32  = (int*)alloc((size_t)N_TOT * 4);
    int* csr    = (int*)alloc((size_t)N_TOT * 4);

    int nbScan = (N_NODES + 255) / 256;             // 391
    int nchunk = (N_TOT + CHUNK_E - 1) / CHUNK_E;   // 104
    int ntiles = (N_NODES + 63) / 64;               // 1563
    hipMemsetAsync(counts, 0, (size_t)N_NODES * 4, stream);
    convert_hist_k<<<(N_TOT + 255) / 256, 256, 0, stream>>>(ei, src32, dst32, counts);
    scan_block<<<nbScan, 256, 0, stream>>>(counts, off, bsum);
    scan_bsum<<<1, 512, 0, stream>>>(bsum, nbScan);
    scan_add<<<nbScan, 256, 0, stream>>>(off, bsum, fill);
    scatter_part_k<<<nchunk * NPART, 256, 0, stream>>>(src32, dst32, fill, csr);

    int nagg = (N_NODES + 3) / 4;
    // layer 0: fp32 x -> bf16 out
    gemm_mfma_k<128, false><<<512, 256, 0, stream>>>(x0, W0, asrc, adst, hb, es, ed, ntiles);
    aggregate_k<true><<<nagg, 256, 0, stream>>>(hb, es, ed, off, csr,
        cbias, bng, bnb, bnm, bnv, xb0);
    // layer 1: bf16 x -> bf16 out
    gemm_mfma_k<64, true><<<1024, 256, 0, stream>>>(xb0, Wl, asrc + HC, adst + HC, hb, es, ed, ntiles);
    aggregate_k<true><<<nagg, 256, 0, stream>>>(hb, es, ed, off, csr,
        cbias + CH, bng + CH, bnb + CH, bnm + CH, bnv + CH, xb1);
    // layer 2: bf16 x -> fp32 out (for MLP)
    gemm_mfma_k<64, true><<<1024, 256, 0, stream>>>(xb1, Wl + (size_t)CH * HC, asrc + 2 * HC, adst + 2 * HC, hb, es, ed, ntiles);
    aggregate_k<false><<<nagg, 256, 0, stream>>>(hb, es, ed, off, csr,
        cbias + 2 * CH, bng + 2 * CH, bnb + 2 * CH, bnm + 2 * CH, bnv + 2 * CH, xf32);

    mlp_k<<<(N_NODES + 255) / 256, 256, 0, stream>>>(xf32, l1w, l1b, l2w, l2b, out);
}